// Round 1
// baseline (15290.358 us; speedup 1.0000x reference)
//
#include <hip/hip_runtime.h>
#include <hip/hip_bf16.h>
#include <stdint.h>

// B=64, T=512, V=50000, E=256, H=512
typedef __attribute__((ext_vector_type(8))) short short8;
typedef __attribute__((ext_vector_type(4))) float f32x4;

static __device__ __forceinline__ unsigned short f2b(float x) {
  union { float f; unsigned u; } v; v.f = x;
  unsigned r = (v.u + 0x7FFFu + ((v.u >> 16) & 1u)) >> 16;
  return (unsigned short)r;
}
static __device__ __forceinline__ float sigm(float x) { return 1.0f / (1.0f + __expf(-x)); }
static __device__ __forceinline__ float tanh_(float x) { return 2.0f / (1.0f + __expf(-2.0f * x)) - 1.0f; }

// ---------------- prep: f32 -> bf16 weight conversion ----------------
__global__ void prep(const float* __restrict__ wihf, const float* __restrict__ whhf,
                     const float* __restrict__ wihb, const float* __restrict__ whhb,
                     const float* __restrict__ wp,
                     unsigned short* __restrict__ wih_bf, unsigned short* __restrict__ whh_bf,
                     unsigned short* __restrict__ wp_bf) {
  int i = blockIdx.x * 256 + threadIdx.x;
  int stride = gridDim.x * 256;
  for (int k = i; k < 2048 * 512; k += stride) { whh_bf[k] = f2b(whhf[k]); whh_bf[2048 * 512 + k] = f2b(whhb[k]); }
  for (int k = i; k < 2048 * 256; k += stride) { wih_bf[k] = f2b(wihf[k]); wih_bf[2048 * 256 + k] = f2b(wihb[k]); }
  for (int k = i; k < 256 * 1024; k += stride) { wp_bf[k] = f2b(wp[k]); }
}

// ---------------- gather: embedding lookup -> emb[t][b][e] bf16 ----------------
__global__ void gather(const int* __restrict__ enc, const float* __restrict__ tab,
                       unsigned short* __restrict__ emb) {
  for (int tok = blockIdx.x; tok < 64 * 512; tok += gridDim.x) {
    int b = tok >> 9, t = tok & 511;
    int id = enc[tok];
    int e = threadIdx.x;
    emb[(size_t)(t * 64 + b) * 256 + e] = f2b(tab[(size_t)id * 256 + e]);
  }
}

// ---------------- the BiLSTM pass (persistent, cross-block h exchange) ----------------
// grid 256: bid = d*128 + q*32 + g   (d=dir, q=batch quarter of 16, g=hidden group of 16)
// 4 waves: wave w owns gate-type w (i,f,g,o) for all 16 batch rows of the quarter.
// Whh/Wih fragments live in VGPRs; h exchanged via agent-scope atomics + counter.
__global__ __launch_bounds__(256, 1) void lstm(
    const unsigned short* __restrict__ emb,   // [T][64][256] bf16
    const unsigned short* __restrict__ whh,   // [2][2048][512] bf16
    const unsigned short* __restrict__ wih,   // [2][2048][256] bf16
    const float* __restrict__ bf_, const float* __restrict__ bb_,
    const int* __restrict__ lens,
    unsigned long long* __restrict__ hex_,    // [2][2][64][512] bf16 (u64 = 4 elems)
    unsigned int* __restrict__ cnt,           // 8 counters, 64B apart
    float* __restrict__ out_h,                // [64][512][1024]
    float* __restrict__ out_hn,               // [2][64][512]
    float* __restrict__ out_cn)
{
  const int bid = blockIdx.x;
  const int d = bid >> 7, q = (bid >> 5) & 3, g = bid & 31;
  const int tid = threadIdx.x;
  const int wv = tid >> 6, lane = tid & 63;
  const int l15 = lane & 15, lhi = lane >> 4;

  __shared__ unsigned short lds_h[16 * 512];      // 16 batch rows x 512 hid, XOR-swizzled
  __shared__ float gbuf[4][16][17];               // [gate][hid][batch]
  __shared__ unsigned short hnew[16][16];         // [batch][hid] carry-h bf16

  // --- persistent B fragments (Whh, Wih rows for this wave's gate type) ---
  short8 Bh[16], Bx[8];
  {
    const int row = wv * 512 + g * 16 + l15;
    const unsigned short* pw = whh + ((size_t)d * 2048 + row) * 512 + lhi * 8;
#pragma unroll
    for (int kk = 0; kk < 16; ++kk) Bh[kk] = *(const short8*)(pw + kk * 32);
    const unsigned short* px = wih + ((size_t)d * 2048 + row) * 256 + lhi * 8;
#pragma unroll
    for (int kk = 0; kk < 8; ++kk) Bx[kk] = *(const short8*)(px + kk * 32);
  }
  const float bias = (d ? bb_ : bf_)[wv * 512 + g * 16 + l15];

  // --- cell-state thread mapping: (batch cb, hid ch) ---
  const int cb = tid & 15, ch = tid >> 4;
  const int gb = q * 16 + cb;
  const int mylen = lens[gb];
  float c_st = 0.f, h_cy = 0.f;

  unsigned int* myc = cnt + (d * 4 + q) * 16;

  for (int s = 0; s < 512; ++s) {
    const int t = d ? (511 - s) : s;

    // x projection (independent of h) — overlaps the wait
    f32x4 acc = { bias, bias, bias, bias };
    {
      const unsigned short* xa = emb + ((size_t)(t * 64 + q * 16 + l15)) * 256 + lhi * 8;
#pragma unroll
      for (int kk = 0; kk < 8; ++kk) {
        short8 a = *(const short8*)(xa + kk * 32);
        acc = __builtin_amdgcn_mfma_f32_16x16x32_bf16(a, Bx[kk], acc, 0, 0, 0);
      }
    }

    // wait for h(s-1) from all 32 blocks of this (dir,quarter) group
    if (s > 0) {
      const unsigned int tgt = 32u * (unsigned)s;
      if (lane == 0) {
        while (__hip_atomic_load(myc, __ATOMIC_RELAXED, __HIP_MEMORY_SCOPE_AGENT) < tgt)
          __builtin_amdgcn_s_sleep(1);
      }
      __builtin_amdgcn_fence(__ATOMIC_ACQUIRE, "agent");
    }

    // cooperative load of h slice (16 rows x 512) as coherent 8B atomics
    unsigned long long hv[8];
    {
      const unsigned long long* src = hex_ + ((size_t)((s & 1) * 2 + d) * 64 + q * 16) * 128;
#pragma unroll
      for (int j = 0; j < 8; ++j)
        hv[j] = __hip_atomic_load(src + tid + j * 256, __ATOMIC_RELAXED, __HIP_MEMORY_SCOPE_AGENT);
    }
    __syncthreads();   // previous step's lds_h reads are done before overwrite
    {
#pragma unroll
      for (int j = 0; j < 8; ++j) {
        int o = tid * 8 + j * 2048;
        int r = o >> 10;
        *(unsigned long long*)((char*)lds_h + (o ^ ((r & 7) << 4))) = hv[j];
      }
    }
    __syncthreads();

    // recurrent part: gates += h @ Whh^T
    {
      const int rb0 = l15 * 1024 + lhi * 16;
      const int swz = (l15 & 7) << 4;
#pragma unroll
      for (int kk = 0; kk < 16; ++kk) {
        short8 a = *(const short8*)((const char*)lds_h + ((rb0 + kk * 64) ^ swz));
        acc = __builtin_amdgcn_mfma_f32_16x16x32_bf16(a, Bh[kk], acc, 0, 0, 0);
      }
    }

    // exchange gates between waves: gbuf[gate][hid][batch]
#pragma unroll
    for (int r = 0; r < 4; ++r) gbuf[wv][l15][lhi * 4 + r] = acc[r];
    __syncthreads();

    // cell update (one (batch,hid) per thread), masked by seq length
    {
      float gi = gbuf[0][ch][cb], gf = gbuf[1][ch][cb], gg = gbuf[2][ch][cb], go = gbuf[3][ch][cb];
      float cn_ = sigm(gf) * c_st + sigm(gi) * tanh_(gg);
      float hn_ = sigm(go) * tanh_(cn_);
      bool m = (t < mylen);
      c_st = m ? cn_ : c_st;
      h_cy = m ? hn_ : h_cy;
      hnew[cb][ch] = f2b(h_cy);
      out_h[((size_t)gb * 512 + t) * 1024 + d * 512 + g * 16 + ch] = m ? hn_ : 0.f;
      if (s == 511) {
        size_t o = ((size_t)d * 64 + gb) * 512 + g * 16 + ch;
        out_hn[o] = h_cy;
        out_cn[o] = c_st;
      }
    }
    __syncthreads();

    // publish carry-h (bf16) for next step + release counter
    if (wv == 0) {
      int r = lane >> 2, c4 = lane & 3;
      unsigned long long v = ((const unsigned long long*)hnew)[lane];
      unsigned long long* dst = hex_ +
          ((size_t)(((s + 1) & 1) * 2 + d) * 64 + q * 16 + r) * 128 + g * 4 + c4;
      __hip_atomic_store(dst, v, __ATOMIC_RELAXED, __HIP_MEMORY_SCOPE_AGENT);
      if (lane == 0) {
        __builtin_amdgcn_fence(__ATOMIC_RELEASE, "agent");
        __hip_atomic_fetch_add(myc, 1u, __ATOMIC_RELAXED, __HIP_MEMORY_SCOPE_AGENT);
      }
    }
  }
}

// ---------------- UNK re-embedding: new_emb = [fwd_ctx, bwd_ctx] @ Wp^T + bp ----------------
// 16 tokens per block; MFMA 16x16x32: A = ctx rows (per-lane token), B = Wp rows.
__global__ __launch_bounds__(256, 1) void unkproj(
    const int* __restrict__ enc, const int* __restrict__ lens,
    const float* __restrict__ h1,             // pass1 h in d_out: [64][512][1024] f32
    const unsigned short* __restrict__ wpb,   // [256][1024] bf16
    const float* __restrict__ bp,
    unsigned short* __restrict__ emb)         // [T][64][256] bf16, updated in place
{
  const int base = blockIdx.x * 16;
  const int tid = threadIdx.x;
  const int wv = tid >> 6, lane = tid & 63;
  const int l15 = lane & 15, lhi = lane >> 4;

  const int tokA = base + l15;
  const int bA = tokA >> 9, tA = tokA & 511;
  const bool unkA = (enc[tokA] == 1) && (tA < lens[bA]);
  if (!__any(unkA)) return;

  const bool fok = (tA > 0), bok = (tA < 511);
  const float* fptr = h1 + ((size_t)bA * 512 + (fok ? tA - 1 : 0)) * 1024;
  const float* bptr = h1 + ((size_t)bA * 512 + (bok ? tA + 1 : 0)) * 1024 + 512;

  f32x4 acc[4] = { {0,0,0,0}, {0,0,0,0}, {0,0,0,0}, {0,0,0,0} };

  // fwd half: k in [0,512)
#pragma unroll 4
  for (int kk = 0; kk < 16; ++kk) {
    const int k = kk * 32 + lhi * 8;
    short8 a;
    if (fok) {
      f32x4 lo = *(const f32x4*)(fptr + k);
      f32x4 hi = *(const f32x4*)(fptr + k + 4);
#pragma unroll
      for (int j = 0; j < 4; ++j) { a[j] = (short)f2b(lo[j]); a[4 + j] = (short)f2b(hi[j]); }
    } else {
      a = short8{0,0,0,0,0,0,0,0};
    }
#pragma unroll
    for (int nt = 0; nt < 4; ++nt) {
      short8 bf = *(const short8*)(wpb + (size_t)(wv * 64 + nt * 16 + l15) * 1024 + k);
      acc[nt] = __builtin_amdgcn_mfma_f32_16x16x32_bf16(a, bf, acc[nt], 0, 0, 0);
    }
  }
  // bwd half: k' in [0,512), Wp column offset +512
#pragma unroll 4
  for (int kk = 0; kk < 16; ++kk) {
    const int k = kk * 32 + lhi * 8;
    short8 a;
    if (bok) {
      f32x4 lo = *(const f32x4*)(bptr + k);
      f32x4 hi = *(const f32x4*)(bptr + k + 4);
#pragma unroll
      for (int j = 0; j < 4; ++j) { a[j] = (short)f2b(lo[j]); a[4 + j] = (short)f2b(hi[j]); }
    } else {
      a = short8{0,0,0,0,0,0,0,0};
    }
#pragma unroll
    for (int nt = 0; nt < 4; ++nt) {
      short8 bf = *(const short8*)(wpb + (size_t)(wv * 64 + nt * 16 + l15) * 1024 + 512 + k);
      acc[nt] = __builtin_amdgcn_mfma_f32_16x16x32_bf16(a, bf, acc[nt], 0, 0, 0);
    }
  }

  // store: C row = token (lhi*4+r), col = e (wv*64+nt*16+l15); only where is_unk
#pragma unroll
  for (int r = 0; r < 4; ++r) {
    int tok = base + lhi * 4 + r;
    int b = tok >> 9, t = tok & 511;
    if (enc[tok] == 1 && t < lens[b]) {
#pragma unroll
      for (int nt = 0; nt < 4; ++nt) {
        int e = wv * 64 + nt * 16 + l15;
        emb[(size_t)(t * 64 + b) * 256 + e] = f2b(acc[nt][r] + bp[e]);
      }
    }
  }
}

// ---------------- host ----------------
extern "C" void kernel_launch(void* const* d_in, const int* in_sizes, int n_in,
                              void* d_out, int out_size, void* d_ws, size_t ws_size,
                              hipStream_t stream) {
  (void)in_sizes; (void)n_in; (void)out_size; (void)ws_size;
  const int*   enc  = (const int*)d_in[0];
  const int*   lens = (const int*)d_in[1];
  const float* tab  = (const float*)d_in[2];
  const float* wihf = (const float*)d_in[3];
  const float* whhf = (const float*)d_in[4];
  const float* bf_  = (const float*)d_in[5];
  const float* wihb = (const float*)d_in[6];
  const float* whhb = (const float*)d_in[7];
  const float* bb_  = (const float*)d_in[8];
  const float* wp   = (const float*)d_in[9];
  const float* bp   = (const float*)d_in[10];

  char* ws = (char*)d_ws;
  unsigned short* emb    = (unsigned short*)(ws);                 // 16,777,216 B
  unsigned short* whh_bf = (unsigned short*)(ws + 16777216);      //  4,194,304 B
  unsigned short* wih_bf = (unsigned short*)(ws + 20971520);      //  2,097,152 B
  unsigned short* wp_bf  = (unsigned short*)(ws + 23068672);      //    524,288 B
  unsigned long long* hex1 = (unsigned long long*)(ws + 23592960);//    262,144 B
  unsigned long long* hex2 = (unsigned long long*)(ws + 23855104);//    262,144 B
  unsigned int* cnt1 = (unsigned int*)(ws + 24117248);            //        512 B
  unsigned int* cnt2 = (unsigned int*)(ws + 24117760);            //        512 B

  float* out_h  = (float*)d_out;
  float* out_hn = out_h + (size_t)64 * 512 * 1024;
  float* out_cn = out_hn + 2 * 64 * 512;

  // zero h-exchange buffers + counters (required every call for graph replay)
  hipMemsetAsync(ws + 23592960, 0, 524288 + 1024, stream);

  prep<<<2048, 256, 0, stream>>>(wihf, whhf, wihb, whhb, wp, wih_bf, whh_bf, wp_bf);
  gather<<<4096, 256, 0, stream>>>(enc, tab, emb);

  // pass 1: h -> d_out (scratch)
  lstm<<<256, 256, 0, stream>>>(emb, whh_bf, wih_bf, bf_, bb_, lens, hex1, cnt1,
                                out_h, out_hn, out_cn);
  // UNK context projection, rewrites embedded rows in place
  unkproj<<<2048, 256, 0, stream>>>(enc, lens, out_h, wp_bf, bp, emb);
  // pass 2: final h, h_n, c_n
  lstm<<<256, 256, 0, stream>>>(emb, whh_bf, wih_bf, bf_, bb_, lens, hex2, cnt2,
                                out_h, out_hn, out_cn);
}

// Round 2
// 4502.735 us; speedup vs baseline: 3.3958x; 3.3958x over previous
//
#include <hip/hip_runtime.h>
#include <hip/hip_bf16.h>
#include <stdint.h>

// B=64, T=512, V=50000, E=256, H=512
typedef __attribute__((ext_vector_type(8))) short short8;
typedef __attribute__((ext_vector_type(4))) float f32x4;
typedef __attribute__((ext_vector_type(4))) unsigned int u32x4;

static __device__ __forceinline__ unsigned short f2b(float x) {
  union { float f; unsigned u; } v; v.f = x;
  unsigned r = (v.u + 0x7FFFu + ((v.u >> 16) & 1u)) >> 16;
  return (unsigned short)r;
}
static __device__ __forceinline__ float sigm(float x) { return 1.0f / (1.0f + __expf(-x)); }
static __device__ __forceinline__ float tanh_(float x) { return 2.0f / (1.0f + __expf(-2.0f * x)) - 1.0f; }

// ---------------- prep: f32 -> bf16 weight conversion ----------------
__global__ void prep(const float* __restrict__ wihf, const float* __restrict__ whhf,
                     const float* __restrict__ wihb, const float* __restrict__ whhb,
                     const float* __restrict__ wp,
                     unsigned short* __restrict__ wih_bf, unsigned short* __restrict__ whh_bf,
                     unsigned short* __restrict__ wp_bf) {
  int i = blockIdx.x * 256 + threadIdx.x;
  int stride = gridDim.x * 256;
  for (int k = i; k < 2048 * 512; k += stride) { whh_bf[k] = f2b(whhf[k]); whh_bf[2048 * 512 + k] = f2b(whhb[k]); }
  for (int k = i; k < 2048 * 256; k += stride) { wih_bf[k] = f2b(wihf[k]); wih_bf[2048 * 256 + k] = f2b(wihb[k]); }
  for (int k = i; k < 256 * 1024; k += stride) { wp_bf[k] = f2b(wp[k]); }
}

// ---------------- gather: embedding lookup -> emb[t][b][e] bf16 ----------------
__global__ void gather(const int* __restrict__ enc, const float* __restrict__ tab,
                       unsigned short* __restrict__ emb) {
  for (int tok = blockIdx.x; tok < 64 * 512; tok += gridDim.x) {
    int b = tok >> 9, t = tok & 511;
    int id = enc[tok];
    int e = threadIdx.x;
    emb[(size_t)(t * 64 + b) * 256 + e] = f2b(tab[(size_t)id * 256 + e]);
  }
}

// ---------------- the BiLSTM pass (persistent, cross-block h exchange) ----------------
// grid 256: bid = d*128 + q*32 + g   (d=dir, q=batch quarter of 16, g=hidden group of 16)
// 4 waves: wave w owns gate-type w (i,f,g,o) for all 16 batch rows of the quarter.
// Whh/Wih fragments live in VGPRs. h exchanged FENCE-FREE through the coherent
// point (L3) via sc0/sc1 loads/stores; release order = s_waitcnt vmcnt(0) before
// the counter fetch_add. NO __builtin_amdgcn_fence (those emit buffer_inv /
// buffer_wbl2 = whole-L2 invalidate/writeback per step -> round-1's 15us/step).
__global__ __launch_bounds__(256, 1) void lstm(
    const unsigned short* __restrict__ emb,   // [T][64][256] bf16
    const unsigned short* __restrict__ whh,   // [2][2048][512] bf16
    const unsigned short* __restrict__ wih,   // [2][2048][256] bf16
    const float* __restrict__ bf_, const float* __restrict__ bb_,
    const int* __restrict__ lens,
    unsigned long long* __restrict__ hex_,    // [2][2][64 rows][1024B] bf16 h
    unsigned int* __restrict__ cnt,           // 8 counters, 64B apart
    float* __restrict__ out_h,                // [64][512][1024]
    float* __restrict__ out_hn,               // [2][64][512]
    float* __restrict__ out_cn)
{
  const int bid = blockIdx.x;
  const int d = bid >> 7, q = (bid >> 5) & 3, g = bid & 31;
  const int tid = threadIdx.x;
  const int wv = tid >> 6, lane = tid & 63;
  const int l15 = lane & 15, lhi = lane >> 4;

  __shared__ __align__(16) unsigned short lds_h[16 * 512];  // 16 batch rows x 512 hid, XOR-swizzled
  __shared__ float gbuf[4][16][17];               // [gate][hid][batch]
  __shared__ __align__(8) unsigned short hnew[16][16];      // [batch][hid] carry-h bf16

  // --- persistent B fragments (Whh, Wih rows for this wave's gate type) ---
  short8 Bh[16], Bx[8];
  {
    const int row = wv * 512 + g * 16 + l15;
    const unsigned short* pw = whh + ((size_t)d * 2048 + row) * 512 + lhi * 8;
#pragma unroll
    for (int kk = 0; kk < 16; ++kk) Bh[kk] = *(const short8*)(pw + kk * 32);
    const unsigned short* px = wih + ((size_t)d * 2048 + row) * 256 + lhi * 8;
#pragma unroll
    for (int kk = 0; kk < 8; ++kk) Bx[kk] = *(const short8*)(px + kk * 32);
  }
  const float bias = (d ? bb_ : bf_)[wv * 512 + g * 16 + l15];

  // --- cell-state thread mapping: (batch cb, hid ch) ---
  const int cb = tid & 15, ch = tid >> 4;
  const int gb = q * 16 + cb;
  const int mylen = lens[gb];
  float c_st = 0.f, h_cy = 0.f;

  unsigned int* myc = cnt + (d * 4 + q) * 16;

  for (int s = 0; s < 512; ++s) {
    const int t = d ? (511 - s) : s;

    // x projection (independent of h) — overlaps the wait
    f32x4 acc = { bias, bias, bias, bias };
    {
      const unsigned short* xa = emb + ((size_t)(t * 64 + q * 16 + l15)) * 256 + lhi * 8;
#pragma unroll
      for (int kk = 0; kk < 8; ++kk) {
        short8 a = *(const short8*)(xa + kk * 32);
        acc = __builtin_amdgcn_mfma_f32_16x16x32_bf16(a, Bx[kk], acc, 0, 0, 0);
      }
    }

    // wait for h(s-1) from all 32 blocks of this (dir,quarter) group
    if (s > 0) {
      const unsigned int tgt = 32u * (unsigned)s;
      if (lane == 0) {
        while (__hip_atomic_load(myc, __ATOMIC_RELAXED, __HIP_MEMORY_SCOPE_AGENT) < tgt)
          __builtin_amdgcn_s_sleep(1);
      }
      // no fence: sc0/sc1 loads below bypass L1/L2, L3 is coherent.
    }

    // cooperative coherent load of h slice: 64B contiguous per thread
    u32x4 hv0, hv1, hv2, hv3;
    {
      const char* src = (const char*)hex_ +
          ((size_t)((s & 1) * 2 + d) * 64 + q * 16) * 1024 + tid * 64;
      asm volatile(
        "global_load_dwordx4 %0, %4, off sc0 sc1\n\t"
        "global_load_dwordx4 %1, %4, off offset:16 sc0 sc1\n\t"
        "global_load_dwordx4 %2, %4, off offset:32 sc0 sc1\n\t"
        "global_load_dwordx4 %3, %4, off offset:48 sc0 sc1\n\t"
        "s_waitcnt vmcnt(0)"
        : "=&v"(hv0), "=&v"(hv1), "=&v"(hv2), "=&v"(hv3)
        : "v"(src)
        : "memory");
    }
    __syncthreads();   // previous step's lds_h reads are done before overwrite
    {
      const int lrow = tid >> 4;
      const int lc = (tid & 15) * 64;
      const int swz = (lrow & 7) << 4;
      char* base = (char*)lds_h + lrow * 1024;
      *(u32x4*)(base + ((lc +  0) ^ swz)) = hv0;
      *(u32x4*)(base + ((lc + 16) ^ swz)) = hv1;
      *(u32x4*)(base + ((lc + 32) ^ swz)) = hv2;
      *(u32x4*)(base + ((lc + 48) ^ swz)) = hv3;
    }
    __syncthreads();

    // recurrent part: gates += h @ Whh^T
    {
      const int rb0 = l15 * 1024 + lhi * 16;
      const int swz = (l15 & 7) << 4;
#pragma unroll
      for (int kk = 0; kk < 16; ++kk) {
        short8 a = *(const short8*)((const char*)lds_h + ((rb0 + kk * 64) ^ swz));
        acc = __builtin_amdgcn_mfma_f32_16x16x32_bf16(a, Bh[kk], acc, 0, 0, 0);
      }
    }

    // exchange gates between waves: gbuf[gate][hid][batch]
#pragma unroll
    for (int r = 0; r < 4; ++r) gbuf[wv][l15][lhi * 4 + r] = acc[r];
    __syncthreads();

    // cell update (one (batch,hid) per thread), masked by seq length
    float hn_out;
    bool m;
    {
      float gi = gbuf[0][ch][cb], gf = gbuf[1][ch][cb], gg = gbuf[2][ch][cb], go = gbuf[3][ch][cb];
      float cn_ = sigm(gf) * c_st + sigm(gi) * tanh_(gg);
      float hn_ = sigm(go) * tanh_(cn_);
      m = (t < mylen);
      c_st = m ? cn_ : c_st;
      h_cy = m ? hn_ : h_cy;
      hn_out = m ? hn_ : 0.f;
      hnew[cb][ch] = f2b(h_cy);
    }
    __syncthreads();

    // publish carry-h (bf16) for next step + release counter — BEFORE out_h store
    if (wv == 0) {
      unsigned long long v = ((const unsigned long long*)hnew)[lane];
      char* dst = (char*)hex_ +
          ((size_t)(((s + 1) & 1) * 2 + d) * 64 + q * 16 + (lane >> 2)) * 1024 +
          g * 32 + (lane & 3) * 8;
      asm volatile("global_store_dwordx2 %0, %1, off sc0 sc1" :: "v"(dst), "v"(v) : "memory");
      asm volatile("s_waitcnt vmcnt(0)" ::: "memory");   // data at coherent point
      if (lane == 0)
        __hip_atomic_fetch_add(myc, 1u, __ATOMIC_RELAXED, __HIP_MEMORY_SCOPE_AGENT);
    }

    // output stores (cached path, off the critical chain)
    out_h[((size_t)gb * 512 + t) * 1024 + d * 512 + g * 16 + ch] = hn_out;
    if (s == 511) {
      size_t o = ((size_t)d * 64 + gb) * 512 + g * 16 + ch;
      out_hn[o] = h_cy;
      out_cn[o] = c_st;
    }
  }
}

// ---------------- UNK re-embedding: new_emb = [fwd_ctx, bwd_ctx] @ Wp^T + bp ----------------
__global__ __launch_bounds__(256, 1) void unkproj(
    const int* __restrict__ enc, const int* __restrict__ lens,
    const float* __restrict__ h1,             // pass1 h in d_out: [64][512][1024] f32
    const unsigned short* __restrict__ wpb,   // [256][1024] bf16
    const float* __restrict__ bp,
    unsigned short* __restrict__ emb)         // [T][64][256] bf16, updated in place
{
  const int base = blockIdx.x * 16;
  const int tid = threadIdx.x;
  const int wv = tid >> 6, lane = tid & 63;
  const int l15 = lane & 15, lhi = lane >> 4;

  const int tokA = base + l15;
  const int bA = tokA >> 9, tA = tokA & 511;
  const bool unkA = (enc[tokA] == 1) && (tA < lens[bA]);
  if (!__any(unkA)) return;

  const bool fok = (tA > 0), bok = (tA < 511);
  const float* fptr = h1 + ((size_t)bA * 512 + (fok ? tA - 1 : 0)) * 1024;
  const float* bptr = h1 + ((size_t)bA * 512 + (bok ? tA + 1 : 0)) * 1024 + 512;

  f32x4 acc[4] = { {0,0,0,0}, {0,0,0,0}, {0,0,0,0}, {0,0,0,0} };

#pragma unroll 4
  for (int kk = 0; kk < 16; ++kk) {
    const int k = kk * 32 + lhi * 8;
    short8 a;
    if (fok) {
      f32x4 lo = *(const f32x4*)(fptr + k);
      f32x4 hi = *(const f32x4*)(fptr + k + 4);
#pragma unroll
      for (int j = 0; j < 4; ++j) { a[j] = (short)f2b(lo[j]); a[4 + j] = (short)f2b(hi[j]); }
    } else {
      a = short8{0,0,0,0,0,0,0,0};
    }
#pragma unroll
    for (int nt = 0; nt < 4; ++nt) {
      short8 bf = *(const short8*)(wpb + (size_t)(wv * 64 + nt * 16 + l15) * 1024 + k);
      acc[nt] = __builtin_amdgcn_mfma_f32_16x16x32_bf16(a, bf, acc[nt], 0, 0, 0);
    }
  }
#pragma unroll 4
  for (int kk = 0; kk < 16; ++kk) {
    const int k = kk * 32 + lhi * 8;
    short8 a;
    if (bok) {
      f32x4 lo = *(const f32x4*)(bptr + k);
      f32x4 hi = *(const f32x4*)(bptr + k + 4);
#pragma unroll
      for (int j = 0; j < 4; ++j) { a[j] = (short)f2b(lo[j]); a[4 + j] = (short)f2b(hi[j]); }
    } else {
      a = short8{0,0,0,0,0,0,0,0};
    }
#pragma unroll
    for (int nt = 0; nt < 4; ++nt) {
      short8 bf = *(const short8*)(wpb + (size_t)(wv * 64 + nt * 16 + l15) * 1024 + 512 + k);
      acc[nt] = __builtin_amdgcn_mfma_f32_16x16x32_bf16(a, bf, acc[nt], 0, 0, 0);
    }
  }

#pragma unroll
  for (int r = 0; r < 4; ++r) {
    int tok = base + lhi * 4 + r;
    int b = tok >> 9, t = tok & 511;
    if (enc[tok] == 1 && t < lens[b]) {
#pragma unroll
      for (int nt = 0; nt < 4; ++nt) {
        int e = wv * 64 + nt * 16 + l15;
        emb[(size_t)(t * 64 + b) * 256 + e] = f2b(acc[nt][r] + bp[e]);
      }
    }
  }
}

// ---------------- host ----------------
extern "C" void kernel_launch(void* const* d_in, const int* in_sizes, int n_in,
                              void* d_out, int out_size, void* d_ws, size_t ws_size,
                              hipStream_t stream) {
  (void)in_sizes; (void)n_in; (void)out_size; (void)ws_size;
  const int*   enc  = (const int*)d_in[0];
  const int*   lens = (const int*)d_in[1];
  const float* tab  = (const float*)d_in[2];
  const float* wihf = (const float*)d_in[3];
  const float* whhf = (const float*)d_in[4];
  const float* bf_  = (const float*)d_in[5];
  const float* wihb = (const float*)d_in[6];
  const float* whhb = (const float*)d_in[7];
  const float* bb_  = (const float*)d_in[8];
  const float* wp   = (const float*)d_in[9];
  const float* bp   = (const float*)d_in[10];

  char* ws = (char*)d_ws;
  unsigned short* emb    = (unsigned short*)(ws);                 // 16,777,216 B
  unsigned short* whh_bf = (unsigned short*)(ws + 16777216);      //  4,194,304 B
  unsigned short* wih_bf = (unsigned short*)(ws + 20971520);      //  2,097,152 B
  unsigned short* wp_bf  = (unsigned short*)(ws + 23068672);      //    524,288 B
  unsigned long long* hex1 = (unsigned long long*)(ws + 23592960);//    262,144 B
  unsigned long long* hex2 = (unsigned long long*)(ws + 23855104);//    262,144 B
  unsigned int* cnt1 = (unsigned int*)(ws + 24117248);            //        512 B
  unsigned int* cnt2 = (unsigned int*)(ws + 24117760);            //        512 B

  float* out_h  = (float*)d_out;
  float* out_hn = out_h + (size_t)64 * 512 * 1024;
  float* out_cn = out_hn + 2 * 64 * 512;

  // zero h-exchange buffers + counters (required every call for graph replay)
  hipMemsetAsync(ws + 23592960, 0, 524288 + 1024, stream);

  prep<<<2048, 256, 0, stream>>>(wihf, whhf, wihb, whhb, wp, wih_bf, whh_bf, wp_bf);
  gather<<<4096, 256, 0, stream>>>(enc, tab, emb);

  // pass 1: h -> d_out (scratch)
  lstm<<<256, 256, 0, stream>>>(emb, whh_bf, wih_bf, bf_, bb_, lens, hex1, cnt1,
                                out_h, out_hn, out_cn);
  // UNK context projection, rewrites embedded rows in place
  unkproj<<<2048, 256, 0, stream>>>(enc, lens, out_h, wp_bf, bp, emb);
  // pass 2: final h, h_n, c_n
  lstm<<<256, 256, 0, stream>>>(emb, whh_bf, wih_bf, bf_, bb_, lens, hex2, cnt2,
                                out_h, out_hn, out_cn);
}

// Round 3
// 3412.152 us; speedup vs baseline: 4.4811x; 1.3196x over previous
//
#include <hip/hip_runtime.h>
#include <hip/hip_bf16.h>
#include <stdint.h>

// B=64, T=512, V=50000, E=256, H=512
typedef __attribute__((ext_vector_type(8))) short short8;
typedef __attribute__((ext_vector_type(4))) float f32x4;
typedef __attribute__((ext_vector_type(4))) unsigned int u32x4;

static __device__ __forceinline__ unsigned short f2b(float x) {
  union { float f; unsigned u; } v; v.f = x;
  unsigned r = (v.u + 0x7FFFu + ((v.u >> 16) & 1u)) >> 16;
  return (unsigned short)r;
}
static __device__ __forceinline__ float sigm(float x) { return 1.0f / (1.0f + __expf(-x)); }
static __device__ __forceinline__ float tanh_(float x) { return 2.0f / (1.0f + __expf(-2.0f * x)) - 1.0f; }

// ---- ws layout (bytes) ----
#define WS_EMB   0u          // 16,777,216
#define WS_WHH   16777216u   //  4,194,304
#define WS_WIH   20971520u   //  2,097,152
#define WS_WPB   23068672u   //    524,288
#define WS_SYNC  23592960u
#define WS_HEXS1 (WS_SYNC + 0u)        // 262,144  slow hex pass1
#define WS_HEXS2 (WS_SYNC + 262144u)   // 262,144
#define WS_HEXF1 (WS_SYNC + 524288u)   // 262,144  fast hex pass1: 8 grp x 32KB
#define WS_HEXF2 (WS_SYNC + 786432u)   // 262,144
#define WS_CNTS1 (WS_SYNC + 1048576u)  // 4,096
#define WS_CNTS2 (WS_SYNC + 1052672u)
#define WS_CNTF1 (WS_SYNC + 1056768u)
#define WS_CNTF2 (WS_SYNC + 1060864u)
#define WS_REG1  (WS_SYNC + 1064960u)  // 512
#define WS_REG2  (WS_SYNC + 1065472u)  // 512
#define WS_SYNC_SPAN 1065984u

// ---------------- prep: f32 -> bf16 weight conversion ----------------
__global__ void prep(const float* __restrict__ wihf, const float* __restrict__ whhf,
                     const float* __restrict__ wihb, const float* __restrict__ whhb,
                     const float* __restrict__ wp,
                     unsigned short* __restrict__ wih_bf, unsigned short* __restrict__ whh_bf,
                     unsigned short* __restrict__ wp_bf) {
  int i = blockIdx.x * 256 + threadIdx.x;
  int stride = gridDim.x * 256;
  for (int k = i; k < 2048 * 512; k += stride) { whh_bf[k] = f2b(whhf[k]); whh_bf[2048 * 512 + k] = f2b(whhb[k]); }
  for (int k = i; k < 2048 * 256; k += stride) { wih_bf[k] = f2b(wihf[k]); wih_bf[2048 * 256 + k] = f2b(wihb[k]); }
  for (int k = i; k < 256 * 1024; k += stride) { wp_bf[k] = f2b(wp[k]); }
}

// ---------------- gather: embedding lookup -> emb[t][b][e] bf16 ----------------
__global__ void gather(const int* __restrict__ enc, const float* __restrict__ tab,
                       unsigned short* __restrict__ emb) {
  for (int tok = blockIdx.x; tok < 64 * 512; tok += gridDim.x) {
    int b = tok >> 9, t = tok & 511;
    int id = enc[tok];
    int e = threadIdx.x;
    emb[(size_t)(t * 64 + b) * 256 + e] = f2b(tab[(size_t)id * 256 + e]);
  }
}

// ---------------- BiLSTM body (templated on exchange path) ----------------
// FAST=1: whole (d,q) group on one XCD -> sc0-only (L2-coherent) exchange.
// FAST=0: groups span XCDs -> sc0 sc1 (L3) exchange (round-2 proven).
template<int FAST>
static __device__ __forceinline__ void lstm_body(
    int d, int q, int g,
    const unsigned short* __restrict__ emb,
    const unsigned short* __restrict__ whh,
    const unsigned short* __restrict__ wih,
    const float* __restrict__ bf_, const float* __restrict__ bb_,
    const int* __restrict__ lens,
    char* __restrict__ hexS, char* __restrict__ hexF,
    unsigned int* __restrict__ myc,
    float* __restrict__ out_h, float* __restrict__ out_hn, float* __restrict__ out_cn,
    unsigned short* lds_h, float (*gbuf)[16][17], unsigned short (*hnew)[16])
{
  const int tid = threadIdx.x;
  const int wv = tid >> 6, lane = tid & 63;
  const int l15 = lane & 15, lhi = lane >> 4;

  // persistent B fragments (Whh/Wih rows for this wave's gate type)
  short8 Bh[16], Bx[8];
  {
    const int row = wv * 512 + g * 16 + l15;
    const unsigned short* pw = whh + ((size_t)d * 2048 + row) * 512 + lhi * 8;
#pragma unroll
    for (int kk = 0; kk < 16; ++kk) Bh[kk] = *(const short8*)(pw + kk * 32);
    const unsigned short* px = wih + ((size_t)d * 2048 + row) * 256 + lhi * 8;
#pragma unroll
    for (int kk = 0; kk < 8; ++kk) Bx[kk] = *(const short8*)(px + kk * 32);
  }
  const float bias = (d ? bb_ : bf_)[wv * 512 + g * 16 + l15];

  const int cb = tid & 15, ch = tid >> 4;
  const int gb = q * 16 + cb;
  const int mylen = lens[gb];
  float c_st = 0.f, h_cy = 0.f;

  char* hexG = FAST ? (hexF + (d * 4 + q) * 32768) : hexS;

  for (int s = 0; s < 512; ++s) {
    const int t = d ? (511 - s) : s;
    const int p = s & 1;

    // x projection (independent of h) — overlaps the wait
    f32x4 acc0 = { bias, bias, bias, bias };
    f32x4 acc1 = { 0.f, 0.f, 0.f, 0.f };
    {
      const unsigned short* xa = emb + ((size_t)(t * 64 + q * 16 + l15)) * 256 + lhi * 8;
#pragma unroll
      for (int kk = 0; kk < 8; ++kk) {
        short8 a = *(const short8*)(xa + kk * 32);
        acc0 = __builtin_amdgcn_mfma_f32_16x16x32_bf16(a, Bx[kk], acc0, 0, 0, 0);
      }
    }

    // wait for h(s-1) from all 32 blocks of this (dir,quarter) group
    if (s > 0) {
      const unsigned int tgt = 32u * (unsigned)s;
      if (lane == 0) {
        if (FAST) {
          for (;;) {
            unsigned c;
            asm volatile("global_load_dword %0, %1, off sc0\n\ts_waitcnt vmcnt(0)"
                         : "=v"(c) : "v"(myc) : "memory");
            if (c >= tgt) break;
            __builtin_amdgcn_s_sleep(1);
          }
        } else {
          while (__hip_atomic_load(myc, __ATOMIC_RELAXED, __HIP_MEMORY_SCOPE_AGENT) < tgt)
            __builtin_amdgcn_s_sleep(1);
        }
      }
    }

    // cooperative coherent load: thread handles (row=tid&15, col-quarter=tid>>4)
    u32x4 hv0, hv1, hv2, hv3;
    {
      const char* src = FAST
          ? hexG + p * 16384 + (tid & 15) * 1024 + (tid >> 4) * 64
          : hexG + ((size_t)(p * 2 + d) * 64 + q * 16 + (tid & 15)) * 1024 + (tid >> 4) * 64;
      if (FAST) {
        asm volatile(
          "global_load_dwordx4 %0, %4, off sc0\n\t"
          "global_load_dwordx4 %1, %4, off offset:16 sc0\n\t"
          "global_load_dwordx4 %2, %4, off offset:32 sc0\n\t"
          "global_load_dwordx4 %3, %4, off offset:48 sc0\n\t"
          "s_waitcnt vmcnt(0)"
          : "=&v"(hv0), "=&v"(hv1), "=&v"(hv2), "=&v"(hv3) : "v"(src) : "memory");
      } else {
        asm volatile(
          "global_load_dwordx4 %0, %4, off sc0 sc1\n\t"
          "global_load_dwordx4 %1, %4, off offset:16 sc0 sc1\n\t"
          "global_load_dwordx4 %2, %4, off offset:32 sc0 sc1\n\t"
          "global_load_dwordx4 %3, %4, off offset:48 sc0 sc1\n\t"
          "s_waitcnt vmcnt(0)"
          : "=&v"(hv0), "=&v"(hv1), "=&v"(hv2), "=&v"(hv3) : "v"(src) : "memory");
      }
    }
    __syncthreads();   // previous step's lds_h reads done before overwrite
    {
      const int row = tid & 15;
      const int qt = tid >> 4;
      const int swz = (row & 7) << 4;
      char* base = (char*)lds_h + row * 1024;
      *(u32x4*)(base + ((qt * 64 +  0) ^ swz)) = hv0;   // 2-way max on writes now
      *(u32x4*)(base + ((qt * 64 + 16) ^ swz)) = hv1;
      *(u32x4*)(base + ((qt * 64 + 32) ^ swz)) = hv2;
      *(u32x4*)(base + ((qt * 64 + 48) ^ swz)) = hv3;
    }
    __syncthreads();

    // recurrent part: two interleaved 8-deep MFMA chains
    {
      const int rb0 = l15 * 1024 + lhi * 16;
      const int swz = (l15 & 7) << 4;
#pragma unroll
      for (int kk = 0; kk < 16; kk += 2) {
        short8 a0 = *(const short8*)((const char*)lds_h + ((rb0 + kk * 64) ^ swz));
        short8 a1 = *(const short8*)((const char*)lds_h + ((rb0 + (kk + 1) * 64) ^ swz));
        acc0 = __builtin_amdgcn_mfma_f32_16x16x32_bf16(a0, Bh[kk], acc0, 0, 0, 0);
        acc1 = __builtin_amdgcn_mfma_f32_16x16x32_bf16(a1, Bh[kk + 1], acc1, 0, 0, 0);
      }
    }
    f32x4 acc = acc0 + acc1;

    // exchange gates between waves
#pragma unroll
    for (int r = 0; r < 4; ++r) gbuf[wv][l15][lhi * 4 + r] = acc[r];
    __syncthreads();

    // cell update (one (batch,hid) per thread), masked by seq length
    float hn_out; bool m;
    {
      float gi = gbuf[0][ch][cb], gf = gbuf[1][ch][cb], gg = gbuf[2][ch][cb], go = gbuf[3][ch][cb];
      float cn_ = sigm(gf) * c_st + sigm(gi) * tanh_(gg);
      float hn_ = sigm(go) * tanh_(cn_);
      m = (t < mylen);
      c_st = m ? cn_ : c_st;
      h_cy = m ? hn_ : h_cy;
      hn_out = m ? hn_ : 0.f;
      hnew[cb][ch] = f2b(h_cy);
    }
    __syncthreads();

    // publish carry-h + release counter
    if (wv == 0) {
      unsigned long long v = ((const unsigned long long*)hnew)[lane];
      char* dst = FAST
          ? hexG + ((s + 1) & 1) * 16384 + (lane >> 2) * 1024 + g * 32 + (lane & 3) * 8
          : hexG + ((size_t)(((s + 1) & 1) * 2 + d) * 64 + q * 16 + (lane >> 2)) * 1024 + g * 32 + (lane & 3) * 8;
      if (FAST) {
        asm volatile("global_store_dwordx2 %0, %1, off sc0" :: "v"(dst), "v"(v) : "memory");
        asm volatile("s_waitcnt vmcnt(0)" ::: "memory");
        if (lane == 0)
          __hip_atomic_fetch_add(myc, 1u, __ATOMIC_RELAXED, __HIP_MEMORY_SCOPE_WORKGROUP);
      } else {
        asm volatile("global_store_dwordx2 %0, %1, off sc0 sc1" :: "v"(dst), "v"(v) : "memory");
        asm volatile("s_waitcnt vmcnt(0)" ::: "memory");
        if (lane == 0)
          __hip_atomic_fetch_add(myc, 1u, __ATOMIC_RELAXED, __HIP_MEMORY_SCOPE_AGENT);
      }
    }

    // output stores (cached path, off the critical chain)
    out_h[((size_t)gb * 512 + t) * 1024 + d * 512 + g * 16 + ch] = hn_out;
    if (s == 511) {
      size_t o = ((size_t)d * 64 + gb) * 512 + g * 16 + ch;
      out_hn[o] = h_cy;
      out_cn[o] = c_st;
    }
  }
}

__global__ __launch_bounds__(256, 1) void lstm(
    const unsigned short* __restrict__ emb, const unsigned short* __restrict__ whh,
    const unsigned short* __restrict__ wih,
    const float* __restrict__ bf_, const float* __restrict__ bb_,
    const int* __restrict__ lens,
    char* __restrict__ hexS, char* __restrict__ hexF,
    unsigned int* __restrict__ cntS, unsigned int* __restrict__ cntF,
    unsigned int* __restrict__ reg,
    float* __restrict__ out_h, float* __restrict__ out_hn, float* __restrict__ out_cn)
{
  __shared__ __align__(16) unsigned short lds_h[16 * 512];
  __shared__ float gbuf[4][16][17];
  __shared__ __align__(8) unsigned short hnew[16][16];
  __shared__ int sh[4];

  const int tid = threadIdx.x;
  if (tid == 0) {
    // XCD rendezvous: claim a slot on this block's physical XCD.
    unsigned xcd = 0;
    asm volatile("s_getreg_b32 %0, hwreg(HW_REG_XCC_ID)" : "=s"(xcd));
    xcd &= 7u;
    unsigned slot = __hip_atomic_fetch_add(&reg[xcd], 1u, __ATOMIC_RELAXED, __HIP_MEMORY_SCOPE_AGENT);
    unsigned v[8];
    for (;;) {
      unsigned sm = 0;
#pragma unroll
      for (int i = 0; i < 8; ++i) {
        v[i] = __hip_atomic_load(&reg[i], __ATOMIC_RELAXED, __HIP_MEMORY_SCOPE_AGENT);
        sm += v[i];
      }
      if (sm == 256u) break;   // counts are final & monotone: snapshot==256 => all claims visible
      __builtin_amdgcn_s_sleep(8);
    }
    bool clean = (slot < 32u);
    for (int i = 0; i < 8; ++i) clean = clean && (v[i] == 32u);
    if (clean) { sh[0] = 1; sh[1] = (int)(xcd >> 2); sh[2] = (int)(xcd & 3); sh[3] = (int)slot; }
    else {
      int bid = blockIdx.x;
      sh[0] = 0; sh[1] = bid >> 7; sh[2] = (bid >> 5) & 3; sh[3] = bid & 31;
    }
  }
  __syncthreads();
  const int fast = sh[0], d = sh[1], q = sh[2], g = sh[3];
  unsigned int* myc = (fast ? cntF : cntS) + (d * 4 + q) * 128;

  if (fast)
    lstm_body<1>(d, q, g, emb, whh, wih, bf_, bb_, lens, hexS, hexF, myc,
                 out_h, out_hn, out_cn, lds_h, gbuf, hnew);
  else
    lstm_body<0>(d, q, g, emb, whh, wih, bf_, bb_, lens, hexS, hexF, myc,
                 out_h, out_hn, out_cn, lds_h, gbuf, hnew);
}

// ---------------- UNK re-embedding: new_emb = [fwd_ctx, bwd_ctx] @ Wp^T + bp ----------------
__global__ __launch_bounds__(256, 1) void unkproj(
    const int* __restrict__ enc, const int* __restrict__ lens,
    const float* __restrict__ h1,             // pass1 h in d_out: [64][512][1024] f32
    const unsigned short* __restrict__ wpb,   // [256][1024] bf16
    const float* __restrict__ bp,
    unsigned short* __restrict__ emb)         // [T][64][256] bf16, updated in place
{
  const int base = blockIdx.x * 16;
  const int tid = threadIdx.x;
  const int wv = tid >> 6, lane = tid & 63;
  const int l15 = lane & 15, lhi = lane >> 4;

  const int tokA = base + l15;
  const int bA = tokA >> 9, tA = tokA & 511;
  const bool unkA = (enc[tokA] == 1) && (tA < lens[bA]);
  if (!__any(unkA)) return;

  const bool fok = (tA > 0), bok = (tA < 511);
  const float* fptr = h1 + ((size_t)bA * 512 + (fok ? tA - 1 : 0)) * 1024;
  const float* bptr = h1 + ((size_t)bA * 512 + (bok ? tA + 1 : 0)) * 1024 + 512;

  f32x4 acc[4] = { {0,0,0,0}, {0,0,0,0}, {0,0,0,0}, {0,0,0,0} };

#pragma unroll 4
  for (int kk = 0; kk < 16; ++kk) {
    const int k = kk * 32 + lhi * 8;
    short8 a;
    if (fok) {
      f32x4 lo = *(const f32x4*)(fptr + k);
      f32x4 hi = *(const f32x4*)(fptr + k + 4);
#pragma unroll
      for (int j = 0; j < 4; ++j) { a[j] = (short)f2b(lo[j]); a[4 + j] = (short)f2b(hi[j]); }
    } else {
      a = short8{0,0,0,0,0,0,0,0};
    }
#pragma unroll
    for (int nt = 0; nt < 4; ++nt) {
      short8 bf = *(const short8*)(wpb + (size_t)(wv * 64 + nt * 16 + l15) * 1024 + k);
      acc[nt] = __builtin_amdgcn_mfma_f32_16x16x32_bf16(a, bf, acc[nt], 0, 0, 0);
    }
  }
#pragma unroll 4
  for (int kk = 0; kk < 16; ++kk) {
    const int k = kk * 32 + lhi * 8;
    short8 a;
    if (bok) {
      f32x4 lo = *(const f32x4*)(bptr + k);
      f32x4 hi = *(const f32x4*)(bptr + k + 4);
#pragma unroll
      for (int j = 0; j < 4; ++j) { a[j] = (short)f2b(lo[j]); a[4 + j] = (short)f2b(hi[j]); }
    } else {
      a = short8{0,0,0,0,0,0,0,0};
    }
#pragma unroll
    for (int nt = 0; nt < 4; ++nt) {
      short8 bf = *(const short8*)(wpb + (size_t)(wv * 64 + nt * 16 + l15) * 1024 + 512 + k);
      acc[nt] = __builtin_amdgcn_mfma_f32_16x16x32_bf16(a, bf, acc[nt], 0, 0, 0);
    }
  }

#pragma unroll
  for (int r = 0; r < 4; ++r) {
    int tok = base + lhi * 4 + r;
    int b = tok >> 9, t = tok & 511;
    if (enc[tok] == 1 && t < lens[b]) {
#pragma unroll
      for (int nt = 0; nt < 4; ++nt) {
        int e = wv * 64 + nt * 16 + l15;
        emb[(size_t)(t * 64 + b) * 256 + e] = f2b(acc[nt][r] + bp[e]);
      }
    }
  }
}

// ---------------- host ----------------
extern "C" void kernel_launch(void* const* d_in, const int* in_sizes, int n_in,
                              void* d_out, int out_size, void* d_ws, size_t ws_size,
                              hipStream_t stream) {
  (void)in_sizes; (void)n_in; (void)out_size; (void)ws_size;
  const int*   enc  = (const int*)d_in[0];
  const int*   lens = (const int*)d_in[1];
  const float* tab  = (const float*)d_in[2];
  const float* wihf = (const float*)d_in[3];
  const float* whhf = (const float*)d_in[4];
  const float* bf_  = (const float*)d_in[5];
  const float* wihb = (const float*)d_in[6];
  const float* whhb = (const float*)d_in[7];
  const float* bb_  = (const float*)d_in[8];
  const float* wp   = (const float*)d_in[9];
  const float* bp   = (const float*)d_in[10];

  char* ws = (char*)d_ws;
  unsigned short* emb    = (unsigned short*)(ws + WS_EMB);
  unsigned short* whh_bf = (unsigned short*)(ws + WS_WHH);
  unsigned short* wih_bf = (unsigned short*)(ws + WS_WIH);
  unsigned short* wp_bf  = (unsigned short*)(ws + WS_WPB);

  float* out_h  = (float*)d_out;
  float* out_hn = out_h + (size_t)64 * 512 * 1024;
  float* out_cn = out_hn + 2 * 64 * 512;

  // zero sync region (hexS/hexF/counters/rendezvous) every call for graph replay
  hipMemsetAsync(ws + WS_SYNC, 0, WS_SYNC_SPAN, stream);

  prep<<<2048, 256, 0, stream>>>(wihf, whhf, wihb, whhb, wp, wih_bf, whh_bf, wp_bf);
  gather<<<4096, 256, 0, stream>>>(enc, tab, emb);

  // pass 1: h -> d_out (scratch)
  lstm<<<256, 256, 0, stream>>>(emb, whh_bf, wih_bf, bf_, bb_, lens,
                                ws + WS_HEXS1, ws + WS_HEXF1,
                                (unsigned int*)(ws + WS_CNTS1), (unsigned int*)(ws + WS_CNTF1),
                                (unsigned int*)(ws + WS_REG1),
                                out_h, out_hn, out_cn);
  // UNK context projection, rewrites embedded rows in place
  unkproj<<<2048, 256, 0, stream>>>(enc, lens, out_h, wp_bf, bp, emb);
  // pass 2: final h, h_n, c_n
  lstm<<<256, 256, 0, stream>>>(emb, whh_bf, wih_bf, bf_, bb_, lens,
                                ws + WS_HEXS2, ws + WS_HEXF2,
                                (unsigned int*)(ws + WS_CNTS2), (unsigned int*)(ws + WS_CNTF2),
                                (unsigned int*)(ws + WS_REG2),
                                out_h, out_hn, out_cn);
}